// Round 1
// baseline (1241.541 us; speedup 1.0000x reference)
//
#include <hip/hip_runtime.h>
#include <math.h>

#define H_HERBS 25000
#define DIM 128

// ---------------- K1: segment starts via binary search (indices sorted) ---
__global__ void k_starts(const int* __restrict__ idxA, const int* __restrict__ idxB,
                         int nA, int nB, int* __restrict__ startA, int* __restrict__ startB) {
    int h = blockIdx.x * blockDim.x + threadIdx.x;
    if (h > H_HERBS) return;
    // lower_bound: first i with idx[i] >= h
    {
        int lo = 0, hi = nA;
        while (lo < hi) { int mid = (lo + hi) >> 1; if (idxA[mid] < h) lo = mid + 1; else hi = mid; }
        startA[h] = lo;
    }
    {
        int lo = 0, hi = nB;
        while (lo < hi) { int mid = (lo + hi) >> 1; if (idxB[mid] < h) lo = mid + 1; else hi = mid; }
        startB[h] = lo;
    }
}

// ---------------- K2: per-herb mean of X, projected through aw1[128:256,:] + ab1
// mpart[h][j] = sum_k mean[k]*aw1[(128+k)*64+j] + ab1[j]
__global__ __launch_bounds__(64) void k_mean_mpart(
        const float* __restrict__ X, const int* __restrict__ start,
        const float* __restrict__ aw1, const float* __restrict__ ab1,
        float* __restrict__ mpart) {
    int h = blockIdx.x;
    int lane = threadIdx.x;
    int s = start[h], e = start[h + 1];
    const float2* X2 = (const float2*)X;
    float2 acc = make_float2(0.f, 0.f);
    for (int r = s; r < e; ++r) {
        float2 v = X2[(size_t)r * 64 + lane];
        acc.x += v.x; acc.y += v.y;
    }
    int cnt = e - s;
    float inv = 1.0f / (float)(cnt > 1 ? cnt : 1);
    __shared__ float mean[DIM];
    mean[2 * lane]     = acc.x * inv;
    mean[2 * lane + 1] = acc.y * inv;
    __syncthreads();
    int j = lane;
    float m = ab1[j];
    #pragma unroll 8
    for (int k = 0; k < 128; ++k) {
        m += mean[k] * aw1[(size_t)(128 + k) * 64 + j];
    }
    mpart[(size_t)h * 64 + j] = m;
}

// ---------------- K3: per-item attention score (item-per-lane GEMV) -------
// score_i = ab2 + sum_j leakyrelu( x_i . aw1[0:128,j] + mpart[herb_i][j] ) * aw2[j]
__global__ __launch_bounds__(256) void k_scores(
        const float* __restrict__ X, const int* __restrict__ idx,
        const float* __restrict__ mpart, const float* __restrict__ aw1,
        const float* __restrict__ aw2, const float* __restrict__ ab2,
        float* __restrict__ scores, int n) {
    int i = blockIdx.x * blockDim.x + threadIdx.x;
    if (i >= n) return;

    // keep row in registers (fully static indexing -> no scratch)
    float x[DIM];
    {
        const float4* X4 = (const float4*)(X + (size_t)i * DIM);
        #pragma unroll
        for (int q = 0; q < DIM / 4; ++q) {
            float4 v = X4[q];
            x[4 * q] = v.x; x[4 * q + 1] = v.y; x[4 * q + 2] = v.z; x[4 * q + 3] = v.w;
        }
    }
    int h = idx[i];
    const float4* mp4 = (const float4*)(mpart + (size_t)h * 64);
    const float4* W4  = (const float4*)aw1;   // row k -> 16 float4 groups of j
    const float4* A24 = (const float4*)aw2;

    float score = ab2[0];
    for (int jb = 0; jb < 16; ++jb) {
        float4 hv = mp4[jb];
        #pragma unroll
        for (int k = 0; k < 128; ++k) {
            float xk = x[k];
            float4 w = W4[(size_t)k * 16 + jb];   // lane-uniform -> scalar loads
            hv.x += xk * w.x; hv.y += xk * w.y; hv.z += xk * w.z; hv.w += xk * w.w;
        }
        hv.x = (hv.x > 0.f) ? hv.x : 0.2f * hv.x;
        hv.y = (hv.y > 0.f) ? hv.y : 0.2f * hv.y;
        hv.z = (hv.z > 0.f) ? hv.z : 0.2f * hv.z;
        hv.w = (hv.w > 0.f) ? hv.w : 0.2f * hv.w;
        float4 a2 = A24[jb];
        score += hv.x * a2.x + hv.y * a2.y + hv.z * a2.z + hv.w * a2.w;
    }
    scores[i] = score;
}

// ---------------- K5: per-herb softmax + weighted row sum -----------------
__global__ __launch_bounds__(64) void k_attn_out(
        const float* __restrict__ X, const int* __restrict__ start,
        const float* __restrict__ scores, float* __restrict__ out) {
    int h = blockIdx.x;
    int lane = threadIdx.x;
    int s = start[h], e = start[h + 1];
    const float2* X2 = (const float2*)X;
    float2 acc = make_float2(0.f, 0.f);
    if (e > s) {
        float mx = -INFINITY;
        for (int r = s + lane; r < e; r += 64) mx = fmaxf(mx, scores[r]);
        #pragma unroll
        for (int o = 32; o; o >>= 1) mx = fmaxf(mx, __shfl_xor(mx, o, 64));
        float sum = 0.f;
        for (int r = s + lane; r < e; r += 64) sum += __expf(scores[r] - mx);
        #pragma unroll
        for (int o = 32; o; o >>= 1) sum += __shfl_xor(sum, o, 64);
        float invden = 1.0f / (sum + 1e-16f);
        for (int r = s; r < e; ++r) {
            float wgt = __expf(scores[r] - mx) * invden;   // lane-uniform
            float2 v = X2[(size_t)r * 64 + lane];
            acc.x += wgt * v.x; acc.y += wgt * v.y;
        }
    }
    float2* O2 = (float2*)out;
    O2[(size_t)h * 64 + lane] = acc;
}

// ---------------- K6: fusion MLP, 16 herbs per 256-thread block -----------
#define HPB 16
__global__ __launch_bounds__(256) void k_fusion(
        const float* __restrict__ HA, const float* __restrict__ HB,
        const float* __restrict__ fw1, const float* __restrict__ fb1,
        const float* __restrict__ fw2, const float* __restrict__ fb2,
        float* __restrict__ out) {
    __shared__ float feat[HPB][512];
    __shared__ float hid[HPB][256];
    int t = threadIdx.x;
    int h0 = blockIdx.x * HPB;

    // build [HA, HB, HA*HB, |HA-HB|] features
    for (int idx = t; idx < HPB * DIM; idx += 256) {
        int hh = idx >> 7, c = idx & 127;
        int h = h0 + hh;
        float a = 0.f, b = 0.f;
        if (h < H_HERBS) { a = HA[(size_t)h * DIM + c]; b = HB[(size_t)h * DIM + c]; }
        feat[hh][c]       = a;
        feat[hh][128 + c] = b;
        feat[hh][256 + c] = a * b;
        feat[hh][384 + c] = fabsf(a - b);
    }
    __syncthreads();

    // layer 1: thread t owns hidden column t
    float acc[HPB];
    #pragma unroll
    for (int hh = 0; hh < HPB; ++hh) acc[hh] = 0.f;
    #pragma unroll 4
    for (int k = 0; k < 512; ++k) {
        float w = fw1[(size_t)k * 256 + t];   // coalesced
        #pragma unroll
        for (int hh = 0; hh < HPB; ++hh) acc[hh] += feat[hh][k] * w;  // broadcast reads
    }
    float b1 = fb1[t];
    #pragma unroll
    for (int hh = 0; hh < HPB; ++hh) hid[hh][t] = fmaxf(acc[hh] + b1, 0.f);
    __syncthreads();

    // layer 2: thread t -> col = t&127, herb-group = t>>7 (8 herbs each)
    int col = t & 127, g = t >> 7;
    float acc2[8];
    #pragma unroll
    for (int q = 0; q < 8; ++q) acc2[q] = 0.f;
    #pragma unroll 4
    for (int k = 0; k < 256; ++k) {
        float w = fw2[(size_t)k * 128 + col];
        #pragma unroll
        for (int q = 0; q < 8; ++q) acc2[q] += hid[g * 8 + q][k] * w;
    }
    float b2 = fb2[col];
    #pragma unroll
    for (int q = 0; q < 8; ++q) {
        int h = h0 + g * 8 + q;
        if (h < H_HERBS) out[(size_t)h * DIM + col] = acc2[q] + b2;
    }
}

extern "C" void kernel_launch(void* const* d_in, const int* in_sizes, int n_in,
                              void* d_out, int out_size, void* d_ws, size_t ws_size,
                              hipStream_t stream) {
    const float* hA  = (const float*)d_in[0];
    const float* hB  = (const float*)d_in[1];
    const int*   idxA = (const int*)d_in[2];
    const int*   idxB = (const int*)d_in[3];
    // d_in[4] = num_herbs scalar (25000, hardcoded)
    const float* aw1 = (const float*)d_in[5];
    const float* ab1 = (const float*)d_in[6];
    const float* aw2 = (const float*)d_in[7];
    const float* ab2 = (const float*)d_in[8];
    const float* fw1 = (const float*)d_in[9];
    const float* fb1 = (const float*)d_in[10];
    const float* fw2 = (const float*)d_in[11];
    const float* fb2 = (const float*)d_in[12];

    int nA = in_sizes[0] / DIM;
    int nB = in_sizes[1] / DIM;

    float* out  = (float*)d_out;
    float* outI = out;                                   // H_interaction
    float* outA = out + (size_t)H_HERBS * DIM;           // H_A_given_B
    float* outB = out + (size_t)2 * H_HERBS * DIM;       // H_B_given_A

    // workspace carve
    char* w = (char*)d_ws;
    auto carve = [&](size_t bytes) { char* p = w; w += (bytes + 255) & ~(size_t)255; return p; };
    int*   startA  = (int*)carve((size_t)(H_HERBS + 1) * sizeof(int));
    int*   startB  = (int*)carve((size_t)(H_HERBS + 1) * sizeof(int));
    float* mpartA  = (float*)carve((size_t)H_HERBS * 64 * sizeof(float));
    float* mpartB  = (float*)carve((size_t)H_HERBS * 64 * sizeof(float));
    float* scoresA = (float*)carve((size_t)nA * sizeof(float));
    float* scoresB = (float*)carve((size_t)nB * sizeof(float));

    k_starts<<<(H_HERBS + 1 + 255) / 256, 256, 0, stream>>>(idxA, idxB, nA, nB, startA, startB);

    // mpartA uses mean of B side; mpartB uses mean of A side
    k_mean_mpart<<<H_HERBS, 64, 0, stream>>>(hB, startB, aw1, ab1, mpartA);
    k_mean_mpart<<<H_HERBS, 64, 0, stream>>>(hA, startA, aw1, ab1, mpartB);

    k_scores<<<(nA + 255) / 256, 256, 0, stream>>>(hA, idxA, mpartA, aw1, aw2, ab2, scoresA, nA);
    k_scores<<<(nB + 255) / 256, 256, 0, stream>>>(hB, idxB, mpartB, aw1, aw2, ab2, scoresB, nB);

    k_attn_out<<<H_HERBS, 64, 0, stream>>>(hA, startA, scoresA, outA);
    k_attn_out<<<H_HERBS, 64, 0, stream>>>(hB, startB, scoresB, outB);

    k_fusion<<<(H_HERBS + HPB - 1) / HPB, 256, 0, stream>>>(outA, outB, fw1, fb1, fw2, fb2, outI);
}

// Round 2
// 814.960 us; speedup vs baseline: 1.5234x; 1.5234x over previous
//
#include <hip/hip_runtime.h>
#include <math.h>

#define H_HERBS 25000
#define DIM 128

// ---------------- K1: segment starts via binary search (indices sorted) ---
__global__ void k_starts(const int* __restrict__ idxA, const int* __restrict__ idxB,
                         int nA, int nB, int* __restrict__ startA, int* __restrict__ startB) {
    int h = blockIdx.x * blockDim.x + threadIdx.x;
    if (h > H_HERBS) return;
    {
        int lo = 0, hi = nA;
        while (lo < hi) { int mid = (lo + hi) >> 1; if (idxA[mid] < h) lo = mid + 1; else hi = mid; }
        startA[h] = lo;
    }
    {
        int lo = 0, hi = nB;
        while (lo < hi) { int mid = (lo + hi) >> 1; if (idxB[mid] < h) lo = mid + 1; else hi = mid; }
        startB[h] = lo;
    }
}

// ---------------- K2: per-herb mean of X, projected through aw1[128:256,:] + ab1
__global__ __launch_bounds__(64) void k_mean_mpart(
        const float* __restrict__ X, const int* __restrict__ start,
        const float* __restrict__ aw1, const float* __restrict__ ab1,
        float* __restrict__ mpart) {
    int h = blockIdx.x;
    int lane = threadIdx.x;
    int s = start[h], e = start[h + 1];
    const float2* X2 = (const float2*)X;
    float2 acc = make_float2(0.f, 0.f);
    for (int r = s; r < e; ++r) {
        float2 v = X2[(size_t)r * 64 + lane];
        acc.x += v.x; acc.y += v.y;
    }
    int cnt = e - s;
    float inv = 1.0f / (float)(cnt > 1 ? cnt : 1);
    __shared__ float mean[DIM];
    mean[2 * lane]     = acc.x * inv;
    mean[2 * lane + 1] = acc.y * inv;
    __syncthreads();
    int j = lane;
    float m = ab1[j];
    #pragma unroll 8
    for (int k = 0; k < 128; ++k) {
        m += mean[k] * aw1[(size_t)(128 + k) * 64 + j];
    }
    mpart[(size_t)h * 64 + j] = m;
}

// ---------------- K3: attention scores — LDS-staged register-blocked GEMV
// Each thread: 2 items x 32 hidden-j (8 float4 groups). jh = tid&1 selects
// j-range [jh*32, jh*32+32). Cross-thread reduce via shfl_xor(.,1).
__global__ __launch_bounds__(256) void k_scores(
        const float* __restrict__ X, const int* __restrict__ idx,
        const float* __restrict__ mpart, const float* __restrict__ aw1,
        const float* __restrict__ aw2, const float* __restrict__ ab2,
        float* __restrict__ scores, int n) {
    __shared__ float4 Wl[128 * 16];    // aw1[0:128, :] as float4 rows (32 KB)
    __shared__ float4 A2l[16];         // aw2

    int t = threadIdx.x;
    const float4* W4 = (const float4*)aw1;
    #pragma unroll
    for (int q = 0; q < 8; ++q) Wl[t + 256 * q] = W4[t + 256 * q];
    if (t < 16) A2l[t] = ((const float4*)aw2)[t];
    __syncthreads();

    int pair = t >> 1, jh = t & 1;
    long i0 = (long)blockIdx.x * 256 + pair * 2;
    long i1 = i0 + 1;
    bool v0 = i0 < n, v1 = i1 < n;
    const float4* X0 = (const float4*)(X + (size_t)(v0 ? i0 : 0) * DIM);
    const float4* X1 = (const float4*)(X + (size_t)(v1 ? i1 : 0) * DIM);

    float4 acc0[8], acc1[8];
    #pragma unroll
    for (int q = 0; q < 8; ++q) {
        acc0[q] = make_float4(0.f, 0.f, 0.f, 0.f);
        acc1[q] = make_float4(0.f, 0.f, 0.f, 0.f);
    }

    const float4* Wbase = Wl + jh * 8;
    for (int kq = 0; kq < 32; ++kq) {
        float4 xa = X0[kq];
        float4 xb = X1[kq];
        #pragma unroll
        for (int kk = 0; kk < 4; ++kk) {
            float x0k = (&xa.x)[kk];
            float x1k = (&xb.x)[kk];
            int k = kq * 4 + kk;
            #pragma unroll
            for (int q = 0; q < 8; ++q) {
                float4 w = Wbase[k * 16 + q];
                acc0[q].x += x0k * w.x; acc0[q].y += x0k * w.y;
                acc0[q].z += x0k * w.z; acc0[q].w += x0k * w.w;
                acc1[q].x += x1k * w.x; acc1[q].y += x1k * w.y;
                acc1[q].z += x1k * w.z; acc1[q].w += x1k * w.w;
            }
        }
    }

    // epilogue: + mpart, leakyrelu(0.2), dot aw2, cross-lane combine
    int h0 = v0 ? idx[i0] : 0;
    int h1 = v1 ? idx[i1] : 0;
    const float4* mp0 = (const float4*)(mpart + (size_t)h0 * 64) + jh * 8;
    const float4* mp1 = (const float4*)(mpart + (size_t)h1 * 64) + jh * 8;
    float s0 = 0.f, s1 = 0.f;
    #pragma unroll
    for (int q = 0; q < 8; ++q) {
        float4 m0 = mp0[q], m1 = mp1[q], a2 = A2l[jh * 8 + q];
        float h0x = acc0[q].x + m0.x, h0y = acc0[q].y + m0.y;
        float h0z = acc0[q].z + m0.z, h0w = acc0[q].w + m0.w;
        h0x = h0x > 0.f ? h0x : 0.2f * h0x; h0y = h0y > 0.f ? h0y : 0.2f * h0y;
        h0z = h0z > 0.f ? h0z : 0.2f * h0z; h0w = h0w > 0.f ? h0w : 0.2f * h0w;
        s0 += h0x * a2.x + h0y * a2.y + h0z * a2.z + h0w * a2.w;
        float h1x = acc1[q].x + m1.x, h1y = acc1[q].y + m1.y;
        float h1z = acc1[q].z + m1.z, h1w = acc1[q].w + m1.w;
        h1x = h1x > 0.f ? h1x : 0.2f * h1x; h1y = h1y > 0.f ? h1y : 0.2f * h1y;
        h1z = h1z > 0.f ? h1z : 0.2f * h1z; h1w = h1w > 0.f ? h1w : 0.2f * h1w;
        s1 += h1x * a2.x + h1y * a2.y + h1z * a2.z + h1w * a2.w;
    }
    s0 += __shfl_xor(s0, 1, 64);
    s1 += __shfl_xor(s1, 1, 64);
    if (jh == 0) {
        float b = ab2[0];
        if (v0) scores[i0] = s0 + b;
        if (v1) scores[i1] = s1 + b;
    }
}

// ---------------- K5: per-herb softmax + weighted row sum -----------------
__global__ __launch_bounds__(64) void k_attn_out(
        const float* __restrict__ X, const int* __restrict__ start,
        const float* __restrict__ scores, float* __restrict__ out) {
    int h = blockIdx.x;
    int lane = threadIdx.x;
    int s = start[h], e = start[h + 1];
    const float2* X2 = (const float2*)X;
    float2 acc = make_float2(0.f, 0.f);
    if (e > s) {
        float mx = -INFINITY;
        for (int r = s + lane; r < e; r += 64) mx = fmaxf(mx, scores[r]);
        #pragma unroll
        for (int o = 32; o; o >>= 1) mx = fmaxf(mx, __shfl_xor(mx, o, 64));
        float sum = 0.f;
        for (int r = s + lane; r < e; r += 64) sum += __expf(scores[r] - mx);
        #pragma unroll
        for (int o = 32; o; o >>= 1) sum += __shfl_xor(sum, o, 64);
        float invden = 1.0f / (sum + 1e-16f);
        for (int r = s; r < e; ++r) {
            float wgt = __expf(scores[r] - mx) * invden;
            float2 v = X2[(size_t)r * 64 + lane];
            acc.x += wgt * v.x; acc.y += wgt * v.y;
        }
    }
    float2* O2 = (float2*)out;
    O2[(size_t)h * 64 + lane] = acc;
}

// ---------------- K6: fusion MLP, 16 herbs per 256-thread block -----------
#define HPB 16
__global__ __launch_bounds__(256) void k_fusion(
        const float* __restrict__ HA, const float* __restrict__ HB,
        const float* __restrict__ fw1, const float* __restrict__ fb1,
        const float* __restrict__ fw2, const float* __restrict__ fb2,
        float* __restrict__ out) {
    __shared__ float feat[HPB][512];
    __shared__ float hid[HPB][256];
    int t = threadIdx.x;
    int h0 = blockIdx.x * HPB;

    for (int idx = t; idx < HPB * DIM; idx += 256) {
        int hh = idx >> 7, c = idx & 127;
        int h = h0 + hh;
        float a = 0.f, b = 0.f;
        if (h < H_HERBS) { a = HA[(size_t)h * DIM + c]; b = HB[(size_t)h * DIM + c]; }
        feat[hh][c]       = a;
        feat[hh][128 + c] = b;
        feat[hh][256 + c] = a * b;
        feat[hh][384 + c] = fabsf(a - b);
    }
    __syncthreads();

    float acc[HPB];
    #pragma unroll
    for (int hh = 0; hh < HPB; ++hh) acc[hh] = 0.f;
    #pragma unroll 4
    for (int k = 0; k < 512; ++k) {
        float w = fw1[(size_t)k * 256 + t];
        #pragma unroll
        for (int hh = 0; hh < HPB; ++hh) acc[hh] += feat[hh][k] * w;
    }
    float b1 = fb1[t];
    #pragma unroll
    for (int hh = 0; hh < HPB; ++hh) hid[hh][t] = fmaxf(acc[hh] + b1, 0.f);
    __syncthreads();

    int col = t & 127, g = t >> 7;
    float acc2[8];
    #pragma unroll
    for (int q = 0; q < 8; ++q) acc2[q] = 0.f;
    #pragma unroll 4
    for (int k = 0; k < 256; ++k) {
        float w = fw2[(size_t)k * 128 + col];
        #pragma unroll
        for (int q = 0; q < 8; ++q) acc2[q] += hid[g * 8 + q][k] * w;
    }
    float b2 = fb2[col];
    #pragma unroll
    for (int q = 0; q < 8; ++q) {
        int h = h0 + g * 8 + q;
        if (h < H_HERBS) out[(size_t)h * DIM + col] = acc2[q] + b2;
    }
}

extern "C" void kernel_launch(void* const* d_in, const int* in_sizes, int n_in,
                              void* d_out, int out_size, void* d_ws, size_t ws_size,
                              hipStream_t stream) {
    const float* hA  = (const float*)d_in[0];
    const float* hB  = (const float*)d_in[1];
    const int*   idxA = (const int*)d_in[2];
    const int*   idxB = (const int*)d_in[3];
    const float* aw1 = (const float*)d_in[5];
    const float* ab1 = (const float*)d_in[6];
    const float* aw2 = (const float*)d_in[7];
    const float* ab2 = (const float*)d_in[8];
    const float* fw1 = (const float*)d_in[9];
    const float* fb1 = (const float*)d_in[10];
    const float* fw2 = (const float*)d_in[11];
    const float* fb2 = (const float*)d_in[12];

    int nA = in_sizes[0] / DIM;
    int nB = in_sizes[1] / DIM;

    float* out  = (float*)d_out;
    float* outI = out;
    float* outA = out + (size_t)H_HERBS * DIM;
    float* outB = out + (size_t)2 * H_HERBS * DIM;

    char* w = (char*)d_ws;
    auto carve = [&](size_t bytes) { char* p = w; w += (bytes + 255) & ~(size_t)255; return p; };
    int*   startA  = (int*)carve((size_t)(H_HERBS + 1) * sizeof(int));
    int*   startB  = (int*)carve((size_t)(H_HERBS + 1) * sizeof(int));
    float* mpartA  = (float*)carve((size_t)H_HERBS * 64 * sizeof(float));
    float* mpartB  = (float*)carve((size_t)H_HERBS * 64 * sizeof(float));
    float* scoresA = (float*)carve((size_t)nA * sizeof(float));
    float* scoresB = (float*)carve((size_t)nB * sizeof(float));

    k_starts<<<(H_HERBS + 1 + 255) / 256, 256, 0, stream>>>(idxA, idxB, nA, nB, startA, startB);

    k_mean_mpart<<<H_HERBS, 64, 0, stream>>>(hB, startB, aw1, ab1, mpartA);
    k_mean_mpart<<<H_HERBS, 64, 0, stream>>>(hA, startA, aw1, ab1, mpartB);

    k_scores<<<(nA + 255) / 256, 256, 0, stream>>>(hA, idxA, mpartA, aw1, aw2, ab2, scoresA, nA);
    k_scores<<<(nB + 255) / 256, 256, 0, stream>>>(hB, idxB, mpartB, aw1, aw2, ab2, scoresB, nB);

    k_attn_out<<<H_HERBS, 64, 0, stream>>>(hA, startA, scoresA, outA);
    k_attn_out<<<H_HERBS, 64, 0, stream>>>(hB, startB, scoresB, outB);

    k_fusion<<<(H_HERBS + HPB - 1) / HPB, 256, 0, stream>>>(outA, outB, fw1, fb1, fw2, fb2, outI);
}

// Round 3
// 729.608 us; speedup vs baseline: 1.7017x; 1.1170x over previous
//
#include <hip/hip_runtime.h>
#include <math.h>

#define H_HERBS 25000
#define DIM 128

// ---------------- K1: segment starts via binary search (indices sorted) ---
__global__ void k_starts(const int* __restrict__ idxA, const int* __restrict__ idxB,
                         int nA, int nB, int* __restrict__ startA, int* __restrict__ startB) {
    int h = blockIdx.x * blockDim.x + threadIdx.x;
    if (h > H_HERBS) return;
    {
        int lo = 0, hi = nA;
        while (lo < hi) { int mid = (lo + hi) >> 1; if (idxA[mid] < h) lo = mid + 1; else hi = mid; }
        startA[h] = lo;
    }
    {
        int lo = 0, hi = nB;
        while (lo < hi) { int mid = (lo + hi) >> 1; if (idxB[mid] < h) lo = mid + 1; else hi = mid; }
        startB[h] = lo;
    }
}

// ---------------- K2: per-herb mean projected through aw1[128:256,:] + ab1
// side 0: mean(h_B) -> mpartA ; side 1: mean(h_A) -> mpartB
__global__ __launch_bounds__(64) void k_mean_both(
        const float* __restrict__ hA, const float* __restrict__ hB,
        const int* __restrict__ startA, const int* __restrict__ startB,
        const float* __restrict__ aw1, const float* __restrict__ ab1,
        float* __restrict__ mpartA, float* __restrict__ mpartB) {
    int bid = blockIdx.x;
    bool sideA = bid < H_HERBS;              // sideA==true -> reading B rows
    int h = sideA ? bid : bid - H_HERBS;
    const float* X = sideA ? hB : hA;
    const int* start = sideA ? startB : startA;
    float* mpart = sideA ? mpartA : mpartB;

    int lane = threadIdx.x;
    int s = start[h], e = start[h + 1];
    const float2* X2 = (const float2*)X;
    float2 acc = make_float2(0.f, 0.f);
    for (int r = s; r < e; ++r) {
        float2 v = X2[(size_t)r * 64 + lane];
        acc.x += v.x; acc.y += v.y;
    }
    int cnt = e - s;
    float inv = 1.0f / (float)(cnt > 1 ? cnt : 1);
    __shared__ float mean[DIM];
    mean[2 * lane]     = acc.x * inv;
    mean[2 * lane + 1] = acc.y * inv;
    __syncthreads();
    int j = lane;
    float m = ab1[j];
    #pragma unroll 8
    for (int k = 0; k < 128; ++k) {
        m += mean[k] * aw1[(size_t)(128 + k) * 64 + j];
    }
    mpart[(size_t)h * 64 + j] = m;
}

// ---------------- K3: attention scores, both sides, 4 items x 16 j / thread
__global__ __launch_bounds__(256) void k_scores_both(
        const float* __restrict__ XA, const int* __restrict__ idxA,
        const float* __restrict__ mpartA, int nA, int gridA,
        const float* __restrict__ XB, const int* __restrict__ idxB,
        const float* __restrict__ mpartB, int nB,
        const float* __restrict__ aw1, const float* __restrict__ aw2,
        const float* __restrict__ ab2,
        float* __restrict__ scoresA, float* __restrict__ scoresB) {
    bool isA = (int)blockIdx.x < gridA;
    int blk = isA ? blockIdx.x : blockIdx.x - gridA;
    const float* X = isA ? XA : XB;
    const int* idx = isA ? idxA : idxB;
    const float* mpart = isA ? mpartA : mpartB;
    float* scores = isA ? scoresA : scoresB;
    int n = isA ? nA : nB;

    __shared__ float4 Wl[128 * 16];    // aw1[0:128,:] as float4 (32 KB)
    __shared__ float4 A2l[16];

    int t = threadIdx.x;
    const float4* W4 = (const float4*)aw1;
    #pragma unroll
    for (int q = 0; q < 8; ++q) Wl[t + 256 * q] = W4[t + 256 * q];
    if (t < 16) A2l[t] = ((const float4*)aw2)[t];
    __syncthreads();

    int grp = t >> 2, jq = t & 3;            // 4-way j split, 16 j's each
    long base = (long)blk * 256 + grp * 4;   // this thread's 4 items

    const float4* Xp[4];
    bool valid[4];
    #pragma unroll
    for (int m = 0; m < 4; ++m) {
        valid[m] = (base + m) < n;
        Xp[m] = (const float4*)(X + (size_t)(valid[m] ? base + m : 0) * DIM);
    }

    float4 acc[4][4];
    #pragma unroll
    for (int m = 0; m < 4; ++m)
        #pragma unroll
        for (int q = 0; q < 4; ++q) acc[m][q] = make_float4(0.f, 0.f, 0.f, 0.f);

    const float4* Wbase = Wl + jq * 4;
    for (int kq = 0; kq < 32; ++kq) {
        float4 xv[4];
        #pragma unroll
        for (int m = 0; m < 4; ++m) xv[m] = Xp[m][kq];
        #pragma unroll
        for (int kk = 0; kk < 4; ++kk) {
            float4 w[4];
            #pragma unroll
            for (int q = 0; q < 4; ++q) w[q] = Wbase[(kq * 4 + kk) * 16 + q];
            #pragma unroll
            for (int m = 0; m < 4; ++m) {
                float x = (&xv[m].x)[kk];
                #pragma unroll
                for (int q = 0; q < 4; ++q) {
                    acc[m][q].x += x * w[q].x; acc[m][q].y += x * w[q].y;
                    acc[m][q].z += x * w[q].z; acc[m][q].w += x * w[q].w;
                }
            }
        }
    }

    float b2s = ab2[0];
    #pragma unroll
    for (int m = 0; m < 4; ++m) {
        int h = valid[m] ? idx[base + m] : 0;
        const float4* mp = (const float4*)(mpart + (size_t)h * 64) + jq * 4;
        float s = 0.f;
        #pragma unroll
        for (int q = 0; q < 4; ++q) {
            float4 mv = mp[q], a2 = A2l[jq * 4 + q];
            float hx = acc[m][q].x + mv.x, hy = acc[m][q].y + mv.y;
            float hz = acc[m][q].z + mv.z, hw = acc[m][q].w + mv.w;
            hx = hx > 0.f ? hx : 0.2f * hx; hy = hy > 0.f ? hy : 0.2f * hy;
            hz = hz > 0.f ? hz : 0.2f * hz; hw = hw > 0.f ? hw : 0.2f * hw;
            s += hx * a2.x + hy * a2.y + hz * a2.z + hw * a2.w;
        }
        s += __shfl_xor(s, 1, 64);
        s += __shfl_xor(s, 2, 64);
        if (jq == 0 && valid[m]) scores[base + m] = s + b2s;
    }
}

// ---------------- K4: per-herb softmax + weighted row sum, both sides -----
__global__ __launch_bounds__(64) void k_attn_both(
        const float* __restrict__ hA, const float* __restrict__ hB,
        const int* __restrict__ startA, const int* __restrict__ startB,
        const float* __restrict__ scoresA, const float* __restrict__ scoresB,
        float* __restrict__ outA, float* __restrict__ outB) {
    int bid = blockIdx.x;
    bool sideA = bid < H_HERBS;
    int h = sideA ? bid : bid - H_HERBS;
    const float* X = sideA ? hA : hB;
    const int* start = sideA ? startA : startB;
    const float* scores = sideA ? scoresA : scoresB;
    float* out = sideA ? outA : outB;

    int lane = threadIdx.x;
    int s = start[h], e = start[h + 1];
    const float2* X2 = (const float2*)X;
    float2 acc = make_float2(0.f, 0.f);
    if (e > s) {
        float mx = -INFINITY;
        for (int r = s + lane; r < e; r += 64) mx = fmaxf(mx, scores[r]);
        #pragma unroll
        for (int o = 32; o; o >>= 1) mx = fmaxf(mx, __shfl_xor(mx, o, 64));
        float sum = 0.f;
        for (int r = s + lane; r < e; r += 64) sum += __expf(scores[r] - mx);
        #pragma unroll
        for (int o = 32; o; o >>= 1) sum += __shfl_xor(sum, o, 64);
        float invden = 1.0f / (sum + 1e-16f);
        for (int r = s; r < e; ++r) {
            float wgt = __expf(scores[r] - mx) * invden;
            float2 v = X2[(size_t)r * 64 + lane];
            acc.x += wgt * v.x; acc.y += wgt * v.y;
        }
    }
    float2* O2 = (float2*)out;
    O2[(size_t)h * 64 + lane] = acc;
}

// ---------------- K5: fusion MLP, register-tiled GEMM -----------------
#define HPB 16
__global__ __launch_bounds__(256) void k_fusion(
        const float* __restrict__ HA, const float* __restrict__ HB,
        const float* __restrict__ fw1, const float* __restrict__ fb1,
        const float* __restrict__ fw2, const float* __restrict__ fb2,
        float* __restrict__ out) {
    __shared__ float feat[HPB][512];   // 32 KB
    __shared__ float hid[HPB][256];    // 16 KB
    int t = threadIdx.x;
    int h0 = blockIdx.x * HPB;

    for (int idx = t; idx < HPB * DIM; idx += 256) {
        int hh = idx >> 7, c = idx & 127;
        int h = h0 + hh;
        float a = 0.f, b = 0.f;
        if (h < H_HERBS) { a = HA[(size_t)h * DIM + c]; b = HB[(size_t)h * DIM + c]; }
        feat[hh][c]       = a;
        feat[hh][128 + c] = b;
        feat[hh][256 + c] = a * b;
        feat[hh][384 + c] = fabsf(a - b);
    }
    __syncthreads();

    // layer 1: thread = 4 herbs (g) x 4 cols (c); per 4-k: 4 b128 broadcast + 4 coalesced w
    {
        int c = t & 63, g = t >> 6;
        float4 acc[4];
        #pragma unroll
        for (int m = 0; m < 4; ++m) acc[m] = make_float4(0.f, 0.f, 0.f, 0.f);
        const float4* W1 = (const float4*)fw1;   // row k: 64 float4
        for (int k = 0; k < 512; k += 4) {
            float4 w0 = W1[(size_t)(k + 0) * 64 + c];
            float4 w1 = W1[(size_t)(k + 1) * 64 + c];
            float4 w2 = W1[(size_t)(k + 2) * 64 + c];
            float4 w3 = W1[(size_t)(k + 3) * 64 + c];
            #pragma unroll
            for (int m = 0; m < 4; ++m) {
                float4 f = *(const float4*)&feat[4 * g + m][k];
                acc[m].x += f.x * w0.x + f.y * w1.x + f.z * w2.x + f.w * w3.x;
                acc[m].y += f.x * w0.y + f.y * w1.y + f.z * w2.y + f.w * w3.y;
                acc[m].z += f.x * w0.z + f.y * w1.z + f.z * w2.z + f.w * w3.z;
                acc[m].w += f.x * w0.w + f.y * w1.w + f.z * w2.w + f.w * w3.w;
            }
        }
        float4 b1v = ((const float4*)fb1)[c];
        #pragma unroll
        for (int m = 0; m < 4; ++m) {
            float4 hv;
            hv.x = fmaxf(acc[m].x + b1v.x, 0.f);
            hv.y = fmaxf(acc[m].y + b1v.y, 0.f);
            hv.z = fmaxf(acc[m].z + b1v.z, 0.f);
            hv.w = fmaxf(acc[m].w + b1v.w, 0.f);
            *(float4*)&hid[4 * g + m][4 * c] = hv;
        }
    }
    __syncthreads();

    // layer 2: thread = 2 herbs (g2) x 4 cols (c2)
    {
        int c2 = t & 31, g2 = t >> 5;
        float4 acc[2];
        #pragma unroll
        for (int m = 0; m < 2; ++m) acc[m] = make_float4(0.f, 0.f, 0.f, 0.f);
        const float4* W2 = (const float4*)fw2;   // row k: 32 float4
        for (int k = 0; k < 256; k += 4) {
            float4 w0 = W2[(size_t)(k + 0) * 32 + c2];
            float4 w1 = W2[(size_t)(k + 1) * 32 + c2];
            float4 w2v = W2[(size_t)(k + 2) * 32 + c2];
            float4 w3 = W2[(size_t)(k + 3) * 32 + c2];
            #pragma unroll
            for (int m = 0; m < 2; ++m) {
                float4 hv = *(const float4*)&hid[2 * g2 + m][k];
                acc[m].x += hv.x * w0.x + hv.y * w1.x + hv.z * w2v.x + hv.w * w3.x;
                acc[m].y += hv.x * w0.y + hv.y * w1.y + hv.z * w2v.y + hv.w * w3.y;
                acc[m].z += hv.x * w0.z + hv.y * w1.z + hv.z * w2v.z + hv.w * w3.z;
                acc[m].w += hv.x * w0.w + hv.y * w1.w + hv.z * w2v.w + hv.w * w3.w;
            }
        }
        float4 b2v = ((const float4*)fb2)[c2];
        #pragma unroll
        for (int m = 0; m < 2; ++m) {
            int h = h0 + 2 * g2 + m;
            if (h < H_HERBS) {
                float4 o;
                o.x = acc[m].x + b2v.x; o.y = acc[m].y + b2v.y;
                o.z = acc[m].z + b2v.z; o.w = acc[m].w + b2v.w;
                ((float4*)out)[(size_t)h * 32 + c2] = o;
            }
        }
    }
}

extern "C" void kernel_launch(void* const* d_in, const int* in_sizes, int n_in,
                              void* d_out, int out_size, void* d_ws, size_t ws_size,
                              hipStream_t stream) {
    const float* hA  = (const float*)d_in[0];
    const float* hB  = (const float*)d_in[1];
    const int*   idxA = (const int*)d_in[2];
    const int*   idxB = (const int*)d_in[3];
    const float* aw1 = (const float*)d_in[5];
    const float* ab1 = (const float*)d_in[6];
    const float* aw2 = (const float*)d_in[7];
    const float* ab2 = (const float*)d_in[8];
    const float* fw1 = (const float*)d_in[9];
    const float* fb1 = (const float*)d_in[10];
    const float* fw2 = (const float*)d_in[11];
    const float* fb2 = (const float*)d_in[12];

    int nA = in_sizes[0] / DIM;
    int nB = in_sizes[1] / DIM;

    float* out  = (float*)d_out;
    float* outI = out;
    float* outA = out + (size_t)H_HERBS * DIM;
    float* outB = out + (size_t)2 * H_HERBS * DIM;

    char* w = (char*)d_ws;
    auto carve = [&](size_t bytes) { char* p = w; w += (bytes + 255) & ~(size_t)255; return p; };
    int*   startA  = (int*)carve((size_t)(H_HERBS + 1) * sizeof(int));
    int*   startB  = (int*)carve((size_t)(H_HERBS + 1) * sizeof(int));
    float* mpartA  = (float*)carve((size_t)H_HERBS * 64 * sizeof(float));
    float* mpartB  = (float*)carve((size_t)H_HERBS * 64 * sizeof(float));
    float* scoresA = (float*)carve((size_t)nA * sizeof(float));
    float* scoresB = (float*)carve((size_t)nB * sizeof(float));

    int gridA = (nA + 255) / 256;
    int gridB = (nB + 255) / 256;

    k_starts<<<(H_HERBS + 1 + 255) / 256, 256, 0, stream>>>(idxA, idxB, nA, nB, startA, startB);

    k_mean_both<<<2 * H_HERBS, 64, 0, stream>>>(hA, hB, startA, startB, aw1, ab1, mpartA, mpartB);

    k_scores_both<<<gridA + gridB, 256, 0, stream>>>(hA, idxA, mpartA, nA, gridA,
                                                     hB, idxB, mpartB, nB,
                                                     aw1, aw2, ab2, scoresA, scoresB);

    k_attn_both<<<2 * H_HERBS, 64, 0, stream>>>(hA, hB, startA, startB, scoresA, scoresB, outA, outB);

    k_fusion<<<(H_HERBS + HPB - 1) / HPB, 256, 0, stream>>>(outA, outB, fw1, fb1, fw2, fb2, outI);
}